// Round 4
// baseline (2169.428 us; speedup 1.0000x reference)
//
#include <hip/hip_runtime.h>
#include <hip/hip_bf16.h>
#include <stdint.h>

// QMIX+GAT, register-resident GAT + MFMA hypernet GEMM + in-register epilogue.
// Per block: 32 samples, 4 waves. Phase 1: GAT fully in VGPRs (shfl butterflies
// within 4-lane node groups), writes s as bf16 into rotation-swizzled LDS A-tile.
// Phase 2: MFMA s[32x512] @ B[512x352]; wave (mi,p) owns m-tile mi and n-tiles
// {p, p+2, ..., p+20} so epilogue cols c=32j+e live in acc[j].
// Phase 3: QMIX mixing epilogue straight from accumulators; f32 output.

#define N_AGENTS 8
#define BT       (2048 * 128)
#define ALPHA    0.2f
#define NTILE    22            // 352 / 16
#define KSTEPS   16            // 512 / 32

typedef __attribute__((ext_vector_type(8))) short bf16x8;
typedef __attribute__((ext_vector_type(4))) float f32x4;

__device__ __forceinline__ float leaky(float x) { return x >= 0.f ? x : ALPHA * x; }
__device__ __forceinline__ float elu1(float x)  { return x > 0.f ? x : (__expf(x) - 1.f); }

__device__ __forceinline__ unsigned short f32_to_bf16_rne(float x) {
    uint32_t u = __float_as_uint(x);
    u += 0x7fffu + ((u >> 16) & 1u);
    return (unsigned short)(u >> 16);
}

// -------------------------------------------------- kernel P: pack B (bf16 frags)
// B[512][352] cols: 0..255 hw1 | 256..287 hb1 | 288..319 hwf | 320..351 v1.
// Frag (kt, ni): 64 lanes x 16B; lane l elem e -> B[kt*32+(l>>4)*8+e][ni*16+(l&15)]
__global__ __launch_bounds__(256) void pack_b(
    const float* __restrict__ hw1_w, const float* __restrict__ hb1_w,
    const float* __restrict__ hwf_w, const float* __restrict__ v1_w,
    unsigned short* __restrict__ bpack)
{
    const int g = blockIdx.x * 256 + threadIdx.x;
    if (g >= KSTEPS * NTILE * 64) return;
    const int l  = g & 63;
    const int ni = (g >> 6) % NTILE;
    const int kt = g / (NTILE * 64);
    const int col = ni * 16 + (l & 15);
    const int k0  = kt * 32 + (l >> 4) * 8;
    const float* src; int stride; int c;
    if (col < 256)      { src = hw1_w; stride = 256; c = col; }
    else if (col < 288) { src = hb1_w; stride = 32;  c = col - 256; }
    else if (col < 320) { src = hwf_w; stride = 32;  c = col - 288; }
    else                { src = v1_w;  stride = 32;  c = col - 320; }
    union { unsigned short u[8]; uint4 v; } pk;
    #pragma unroll
    for (int e = 0; e < 8; ++e) pk.u[e] = f32_to_bf16_rne(src[(long)(k0 + e) * stride + c]);
    ((uint4*)bpack)[g] = pk.v;
}

// -------------------------------------------------- kernel F
__global__ __launch_bounds__(256, 3) void fused_kernel(
    const float* __restrict__ agent_qs, const float* __restrict__ states,
    const float* __restrict__ W_heads,  const float* __restrict__ a_heads,
    const float* __restrict__ W_out,    const float* __restrict__ a_out,
    const unsigned short* __restrict__ bpack,
    const float* __restrict__ hw1_b, const float* __restrict__ hb1_b,
    const float* __restrict__ hwf_b, const float* __restrict__ v1_b,
    const float* __restrict__ v2_w,  const float* __restrict__ v2_b,
    float* __restrict__ out)
{
    __shared__ unsigned short A[32][512];  // 32 KB, rotation-swizzled 16B chunks
    __shared__ float WH2[4][16 * 33];      // per-wave Wh2 stash (8.25 KB)
    __shared__ float gw[896];              // Wh[256] ah[32] WoT[32*17] ao[64]
    __shared__ float bst[384];             // hw1_b | hb1_b | hwf_b | v1_b | v2_w
    __shared__ float qs_s[32 * 9];         // padded stride 9
    __shared__ float ysum[4][4][4];        // [wave][g][r]

    const int t    = threadIdx.x;
    const int w    = t >> 6;
    const int lane = t & 63;
    const long sbase = (long)blockIdx.x * 32;

    // ---- stage weights / biases
    gw[t] = W_heads[t];                                   // 256
    if (t < 32) gw[256 + t] = a_heads[t];
    for (int i = t; i < 512; i += 256) {                  // W_out transposed
        const int f = i >> 5, c = i & 31;
        gw[288 + c * 17 + f] = W_out[i];
    }
    if (t < 64) gw[832 + t] = a_out[t];
    if (t < 256) bst[t] = hw1_b[t];
    if (t < 32) {
        bst[256 + t] = hb1_b[t];
        bst[288 + t] = hwf_b[t];
        bst[320 + t] = v1_b[t];
        bst[352 + t] = v2_w[t];
    }
    qs_s[(t >> 3) * 9 + (t & 7)] = agent_qs[sbase * 8 + t];

    #define WHW(h,f,k) gw[(h)*64 + (f)*4 + (k)]
    #define AH(h,i)    gw[256 + (h)*8 + (i)]
    #define WOT(c,f)   gw[288 + (c)*17 + (f)]
    #define AO(c)      gw[832 + (c)]

    __syncthreads();

    const int n  = lane >> 2;   // node 0..15
    const int kq = lane & 3;    // quartet index

    // ---------------- phase 1: GAT (register-resident), 8 samples per wave
    for (int i = 0; i < 8; ++i) {
        const int m = w * 8 + i;
        const float4 xv = ((const float4*)(states + (sbase + m) * 256))[lane];
        float hcat[16];

        #pragma unroll
        for (int h = 0; h < 4; ++h) {
            // Wh[n][k], full value in every lane of node n
            float pk[4];
            #pragma unroll
            for (int k = 0; k < 4; ++k) {
                float v =      xv.x * WHW(h, 4*kq+0, k);
                v = fmaf(xv.y, WHW(h, 4*kq+1, k), v);
                v = fmaf(xv.z, WHW(h, 4*kq+2, k), v);
                v = fmaf(xv.w, WHW(h, 4*kq+3, k), v);
                v += __shfl_xor(v, 1); v += __shfl_xor(v, 2);
                pk[k] = v;
            }
            const float e1 = pk[0]*AH(h,0) + pk[1]*AH(h,1) + pk[2]*AH(h,2) + pk[3]*AH(h,3);
            const float e2 = pk[0]*AH(h,4) + pk[1]*AH(h,5) + pk[2]*AH(h,6) + pk[3]*AH(h,7);
            // softmax over j; lane owns j = 4kq..4kq+3
            float ev[4]; float mx = -1e30f;
            #pragma unroll
            for (int q = 0; q < 4; ++q) {
                ev[q] = leaky(e1 + __shfl(e2, (4*kq + q) * 4));
                mx = fmaxf(mx, ev[q]);
            }
            mx = fmaxf(mx, __shfl_xor(mx, 1));
            mx = fmaxf(mx, __shfl_xor(mx, 2));
            float sum = 0.f;
            #pragma unroll
            for (int q = 0; q < 4; ++q) { ev[q] = __expf(ev[q] - mx); sum += ev[q]; }
            sum += __shfl_xor(sum, 1); sum += __shfl_xor(sum, 2);
            const float inv = 1.f / sum;
            float att[4];
            #pragma unroll
            for (int q = 0; q < 4; ++q) att[q] = ev[q] * inv;
            // h[n][k] = sum_j att[n][j] * Wh[j][k]; partial over own quartet + butterfly
            float po[4] = {0.f, 0.f, 0.f, 0.f};
            #pragma unroll
            for (int q = 0; q < 4; ++q) {
                const int srcl = (4*kq + q) * 4;
                #pragma unroll
                for (int k = 0; k < 4; ++k)
                    po[k] = fmaf(att[q], __shfl(pk[k], srcl), po[k]);
            }
            #pragma unroll
            for (int k = 0; k < 4; ++k) {
                float v = po[k];
                v += __shfl_xor(v, 1); v += __shfl_xor(v, 2);
                hcat[h*4 + k] = elu1(v);
            }
        }

        // ---- output GAT layer; lane owns cols c = kq*8..kq*8+7
        float wh2[8];
        #pragma unroll
        for (int c8 = 0; c8 < 8; ++c8) {
            const int c = kq * 8 + c8;
            float a0 = 0.f;
            #pragma unroll
            for (int f = 0; f < 16; ++f) a0 = fmaf(hcat[f], WOT(c, f), a0);
            wh2[c8] = a0;
        }
        float p1 = 0.f, p2 = 0.f;
        #pragma unroll
        for (int c8 = 0; c8 < 8; ++c8) {
            const int c = kq * 8 + c8;
            p1 = fmaf(wh2[c8], AO(c), p1);
            p2 = fmaf(wh2[c8], AO(32 + c), p2);
        }
        p1 += __shfl_xor(p1, 1); p1 += __shfl_xor(p1, 2);
        p2 += __shfl_xor(p2, 1); p2 += __shfl_xor(p2, 2);

        float ev[4]; float mx = -1e30f;
        #pragma unroll
        for (int q = 0; q < 4; ++q) {
            ev[q] = leaky(p1 + __shfl(p2, (4*kq + q) * 4));
            mx = fmaxf(mx, ev[q]);
        }
        mx = fmaxf(mx, __shfl_xor(mx, 1));
        mx = fmaxf(mx, __shfl_xor(mx, 2));
        float sum = 0.f;
        #pragma unroll
        for (int q = 0; q < 4; ++q) { ev[q] = __expf(ev[q] - mx); sum += ev[q]; }
        sum += __shfl_xor(sum, 1); sum += __shfl_xor(sum, 2);
        const float inv = 1.f / sum;
        float atto[4];
        #pragma unroll
        for (int q = 0; q < 4; ++q) atto[q] = ev[q] * inv;

        // stash wh2; then gat[n][c] = sum_j atto[n][j] * Wh2[j][c]
        float* wv = &WH2[w][n * 33 + kq * 8];
        #pragma unroll
        for (int c8 = 0; c8 < 8; ++c8) wv[c8] = wh2[c8];

        float ga[8] = {0.f,0.f,0.f,0.f,0.f,0.f,0.f,0.f};
        #pragma unroll
        for (int jg = 0; jg < 4; ++jg) {
            #pragma unroll
            for (int q = 0; q < 4; ++q) {
                const float aj = __shfl(atto[q], n * 4 + jg);   // att_o[n][4jg+q]
                const float* wr = &WH2[w][(4*jg + q) * 33 + kq * 8];
                #pragma unroll
                for (int c8 = 0; c8 < 8; ++c8) ga[c8] = fmaf(aj, wr[c8], ga[c8]);
            }
        }
        union { unsigned short us[8]; uint4 v; } pk2;
        #pragma unroll
        for (int c8 = 0; c8 < 8; ++c8) pk2.us[c8] = f32_to_bf16_rne(elu1(ga[c8]));
        // rotation swizzle: logical 16B chunk u = n*4+kq -> phys (kq*16 + n + m) & 63
        const int chunk = (kq * 16 + n + m) & 63;
        *(uint4*)((char*)&A[0][0] + m * 1024 + chunk * 16) = pk2.v;
    }

    __syncthreads();

    // ---------------- phase 2: MFMA GEMM, parity-split n-tiles
    const int mi  = w >> 1;             // m-tile
    const int p   = w & 1;              // n-tile parity: tiles 2j+p
    const int col = lane & 15;
    const int g   = lane >> 4;
    const int arow = mi * 16 + col;

    f32x4 acc[11];
    #pragma unroll
    for (int j = 0; j < 11; ++j) acc[j] = (f32x4){0.f, 0.f, 0.f, 0.f};

    const uint4* Bb = (const uint4*)bpack + lane;
    for (int kt = 0; kt < KSTEPS; ++kt) {
        const int chunk = (g * 16 + kt + arow) & 63;
        bf16x8 af = *(const bf16x8*)((const char*)&A[0][0] + arow * 1024 + chunk * 16);
        const uint4* bp = Bb + (kt * NTILE + p) * 64;
        #pragma unroll
        for (int j = 0; j < 11; ++j) {
            uint4 bw = bp[(2 * j) * 64];
            bf16x8 bf;
            memcpy(&bf, &bw, 16);
            acc[j] = __builtin_amdgcn_mfma_f32_16x16x32_bf16(af, bf, acc[j], 0, 0, 0);
        }
    }

    // ---------------- phase 3: epilogue from accumulators
    // lane covers col e = p*16+col of hyp; samples ms = mi*16 + g*4 + r
    const int e = p * 16 + col;
    float yp[4];
    #pragma unroll
    for (int r = 0; r < 4; ++r) {
        const int ms = mi * 16 + g * 4 + r;
        float hs = acc[8][r] + bst[256 + e];
        #pragma unroll
        for (int a = 0; a < 8; ++a)
            hs = fmaf(qs_s[ms * 9 + a], fabsf(acc[a][r] + bst[a * 32 + e]), hs);
        const float hid = elu1(hs);
        yp[r] = hid * fabsf(acc[9][r] + bst[288 + e])
              + fmaxf(acc[10][r] + bst[320 + e], 0.f) * bst[352 + e];
    }
    #pragma unroll
    for (int mask = 1; mask <= 8; mask <<= 1) {
        #pragma unroll
        for (int r = 0; r < 4; ++r) yp[r] += __shfl_xor(yp[r], mask);
    }
    if (col == 0 && g == (lane >> 4)) {
        #pragma unroll
        for (int r = 0; r < 4; ++r) ysum[w][g][r] = yp[r];
    }
    __syncthreads();

    if (t < 32) {
        const int mi2 = t >> 4, g2 = (t >> 2) & 3, r2 = t & 3;
        out[sbase + t] = ysum[mi2 * 2][g2][r2] + ysum[mi2 * 2 + 1][g2][r2] + v2_b[0];
    }
}

// -------------------------------------------------- launch
extern "C" void kernel_launch(void* const* d_in, const int* in_sizes, int n_in,
                              void* d_out, int out_size, void* d_ws, size_t ws_size,
                              hipStream_t stream) {
    const float* agent_qs = (const float*)d_in[0];
    const float* states   = (const float*)d_in[1];
    const float* W_heads  = (const float*)d_in[2];
    const float* a_heads  = (const float*)d_in[3];
    const float* W_out    = (const float*)d_in[4];
    const float* a_out    = (const float*)d_in[5];
    const float* hw1_w    = (const float*)d_in[6];
    const float* hw1_b    = (const float*)d_in[7];
    const float* hb1_w    = (const float*)d_in[8];
    const float* hb1_b    = (const float*)d_in[9];
    const float* hwf_w    = (const float*)d_in[10];
    const float* hwf_b    = (const float*)d_in[11];
    const float* v1_w     = (const float*)d_in[12];
    const float* v1_b     = (const float*)d_in[13];
    const float* v2_w     = (const float*)d_in[14];
    const float* v2_b     = (const float*)d_in[15];

    unsigned short* bpack = (unsigned short*)d_ws;   // 360448 B used

    pack_b<<<(KSTEPS * NTILE * 64 + 255) / 256, 256, 0, stream>>>(hw1_w, hb1_w, hwf_w, v1_w, bpack);
    fused_kernel<<<BT / 32, 256, 0, stream>>>(agent_qs, states,
                                              W_heads, a_heads, W_out, a_out,
                                              bpack,
                                              hw1_b, hb1_b, hwf_b, v1_b, v2_w, v2_b,
                                              (float*)d_out);
}

// Round 5
// 1680.999 us; speedup vs baseline: 1.2906x; 1.2906x over previous
//
#include <hip/hip_runtime.h>
#include <hip/hip_bf16.h>
#include <stdint.h>

// QMIX+GAT, register-resident GAT + MFMA hypernet GEMM + in-register epilogue.
// Per block: 32 samples, 4 waves. Phase 1: GAT fully in VGPRs (shfl butterflies
// within 4-lane node groups), writes s as bf16 into rotation-swizzled LDS A-tile.
// Phase 2: MFMA s[32x512] @ B[512x352]; wave (mi,p) owns m-tile mi and n-tiles
// {p, p+2, ..., p+20} so epilogue cols c=32j+e live in acc[j].
// Phase 3: QMIX mixing epilogue straight from accumulators; f32 output.
// R5: plain __launch_bounds__(256) — the (256,3) hint forced VGPR=84 and a
//     512B/thread scratch spill (1.07GB writes, 4GB L2-thrash fetches).

#define N_AGENTS 8
#define BT       (2048 * 128)
#define ALPHA    0.2f
#define NTILE    22            // 352 / 16
#define KSTEPS   16            // 512 / 32

typedef __attribute__((ext_vector_type(8))) short bf16x8;
typedef __attribute__((ext_vector_type(4))) float f32x4;

__device__ __forceinline__ float leaky(float x) { return x >= 0.f ? x : ALPHA * x; }
__device__ __forceinline__ float elu1(float x)  { return x > 0.f ? x : (__expf(x) - 1.f); }

__device__ __forceinline__ unsigned short f32_to_bf16_rne(float x) {
    uint32_t u = __float_as_uint(x);
    u += 0x7fffu + ((u >> 16) & 1u);
    return (unsigned short)(u >> 16);
}

// -------------------------------------------------- kernel P: pack B (bf16 frags)
// B[512][352] cols: 0..255 hw1 | 256..287 hb1 | 288..319 hwf | 320..351 v1.
// Frag (kt, ni): 64 lanes x 16B; lane l elem e -> B[kt*32+(l>>4)*8+e][ni*16+(l&15)]
__global__ __launch_bounds__(256) void pack_b(
    const float* __restrict__ hw1_w, const float* __restrict__ hb1_w,
    const float* __restrict__ hwf_w, const float* __restrict__ v1_w,
    unsigned short* __restrict__ bpack)
{
    const int g = blockIdx.x * 256 + threadIdx.x;
    if (g >= KSTEPS * NTILE * 64) return;
    const int l  = g & 63;
    const int ni = (g >> 6) % NTILE;
    const int kt = g / (NTILE * 64);
    const int col = ni * 16 + (l & 15);
    const int k0  = kt * 32 + (l >> 4) * 8;
    const float* src; int stride; int c;
    if (col < 256)      { src = hw1_w; stride = 256; c = col; }
    else if (col < 288) { src = hb1_w; stride = 32;  c = col - 256; }
    else if (col < 320) { src = hwf_w; stride = 32;  c = col - 288; }
    else                { src = v1_w;  stride = 32;  c = col - 320; }
    union { unsigned short u[8]; uint4 v; } pk;
    #pragma unroll
    for (int e = 0; e < 8; ++e) pk.u[e] = f32_to_bf16_rne(src[(long)(k0 + e) * stride + c]);
    ((uint4*)bpack)[g] = pk.v;
}

// -------------------------------------------------- kernel F
__global__ __launch_bounds__(256) void fused_kernel(
    const float* __restrict__ agent_qs, const float* __restrict__ states,
    const float* __restrict__ W_heads,  const float* __restrict__ a_heads,
    const float* __restrict__ W_out,    const float* __restrict__ a_out,
    const unsigned short* __restrict__ bpack,
    const float* __restrict__ hw1_b, const float* __restrict__ hb1_b,
    const float* __restrict__ hwf_b, const float* __restrict__ v1_b,
    const float* __restrict__ v2_w,  const float* __restrict__ v2_b,
    float* __restrict__ out)
{
    __shared__ unsigned short A[32][512];  // 32 KB, rotation-swizzled 16B chunks
    __shared__ float WH2[4][16 * 33];      // per-wave Wh2 stash (8.25 KB)
    __shared__ float gw[896];              // Wh[256] ah[32] WoT[32*17] ao[64]
    __shared__ float bst[384];             // hw1_b | hb1_b | hwf_b | v1_b | v2_w
    __shared__ float qs_s[32 * 9];         // padded stride 9
    __shared__ float ysum[4][4][4];        // [wave][g][r]

    const int t    = threadIdx.x;
    const int w    = t >> 6;
    const int lane = t & 63;
    const long sbase = (long)blockIdx.x * 32;

    // ---- stage weights / biases
    gw[t] = W_heads[t];                                   // 256
    if (t < 32) gw[256 + t] = a_heads[t];
    for (int i = t; i < 512; i += 256) {                  // W_out transposed
        const int f = i >> 5, c = i & 31;
        gw[288 + c * 17 + f] = W_out[i];
    }
    if (t < 64) gw[832 + t] = a_out[t];
    if (t < 256) bst[t] = hw1_b[t];
    if (t < 32) {
        bst[256 + t] = hb1_b[t];
        bst[288 + t] = hwf_b[t];
        bst[320 + t] = v1_b[t];
        bst[352 + t] = v2_w[t];
    }
    qs_s[(t >> 3) * 9 + (t & 7)] = agent_qs[sbase * 8 + t];

    #define WHW(h,f,k) gw[(h)*64 + (f)*4 + (k)]
    #define AH(h,i)    gw[256 + (h)*8 + (i)]
    #define WOT(c,f)   gw[288 + (c)*17 + (f)]
    #define AO(c)      gw[832 + (c)]

    __syncthreads();

    const int n  = lane >> 2;   // node 0..15
    const int kq = lane & 3;    // quartet index

    // ---------------- phase 1: GAT (register-resident), 8 samples per wave
    for (int i = 0; i < 8; ++i) {
        const int m = w * 8 + i;
        const float4 xv = ((const float4*)(states + (sbase + m) * 256))[lane];
        float hcat[16];

        #pragma unroll
        for (int h = 0; h < 4; ++h) {
            // Wh[n][k], full value in every lane of node n
            float pk[4];
            #pragma unroll
            for (int k = 0; k < 4; ++k) {
                float v =      xv.x * WHW(h, 4*kq+0, k);
                v = fmaf(xv.y, WHW(h, 4*kq+1, k), v);
                v = fmaf(xv.z, WHW(h, 4*kq+2, k), v);
                v = fmaf(xv.w, WHW(h, 4*kq+3, k), v);
                v += __shfl_xor(v, 1); v += __shfl_xor(v, 2);
                pk[k] = v;
            }
            const float e1 = pk[0]*AH(h,0) + pk[1]*AH(h,1) + pk[2]*AH(h,2) + pk[3]*AH(h,3);
            const float e2 = pk[0]*AH(h,4) + pk[1]*AH(h,5) + pk[2]*AH(h,6) + pk[3]*AH(h,7);
            // softmax over j; lane owns j = 4kq..4kq+3
            float ev[4]; float mx = -1e30f;
            #pragma unroll
            for (int q = 0; q < 4; ++q) {
                ev[q] = leaky(e1 + __shfl(e2, (4*kq + q) * 4));
                mx = fmaxf(mx, ev[q]);
            }
            mx = fmaxf(mx, __shfl_xor(mx, 1));
            mx = fmaxf(mx, __shfl_xor(mx, 2));
            float sum = 0.f;
            #pragma unroll
            for (int q = 0; q < 4; ++q) { ev[q] = __expf(ev[q] - mx); sum += ev[q]; }
            sum += __shfl_xor(sum, 1); sum += __shfl_xor(sum, 2);
            const float inv = 1.f / sum;
            float att[4];
            #pragma unroll
            for (int q = 0; q < 4; ++q) att[q] = ev[q] * inv;
            // h[n][k] = sum_j att[n][j] * Wh[j][k]; partial over own quartet + butterfly
            float po[4] = {0.f, 0.f, 0.f, 0.f};
            #pragma unroll
            for (int q = 0; q < 4; ++q) {
                const int srcl = (4*kq + q) * 4;
                #pragma unroll
                for (int k = 0; k < 4; ++k)
                    po[k] = fmaf(att[q], __shfl(pk[k], srcl), po[k]);
            }
            #pragma unroll
            for (int k = 0; k < 4; ++k) {
                float v = po[k];
                v += __shfl_xor(v, 1); v += __shfl_xor(v, 2);
                hcat[h*4 + k] = elu1(v);
            }
        }

        // ---- output GAT layer; lane owns cols c = kq*8..kq*8+7
        float wh2[8];
        #pragma unroll
        for (int c8 = 0; c8 < 8; ++c8) {
            const int c = kq * 8 + c8;
            float a0 = 0.f;
            #pragma unroll
            for (int f = 0; f < 16; ++f) a0 = fmaf(hcat[f], WOT(c, f), a0);
            wh2[c8] = a0;
        }
        float p1 = 0.f, p2 = 0.f;
        #pragma unroll
        for (int c8 = 0; c8 < 8; ++c8) {
            const int c = kq * 8 + c8;
            p1 = fmaf(wh2[c8], AO(c), p1);
            p2 = fmaf(wh2[c8], AO(32 + c), p2);
        }
        p1 += __shfl_xor(p1, 1); p1 += __shfl_xor(p1, 2);
        p2 += __shfl_xor(p2, 1); p2 += __shfl_xor(p2, 2);

        float ev[4]; float mx = -1e30f;
        #pragma unroll
        for (int q = 0; q < 4; ++q) {
            ev[q] = leaky(p1 + __shfl(p2, (4*kq + q) * 4));
            mx = fmaxf(mx, ev[q]);
        }
        mx = fmaxf(mx, __shfl_xor(mx, 1));
        mx = fmaxf(mx, __shfl_xor(mx, 2));
        float sum = 0.f;
        #pragma unroll
        for (int q = 0; q < 4; ++q) { ev[q] = __expf(ev[q] - mx); sum += ev[q]; }
        sum += __shfl_xor(sum, 1); sum += __shfl_xor(sum, 2);
        const float inv = 1.f / sum;
        float atto[4];
        #pragma unroll
        for (int q = 0; q < 4; ++q) atto[q] = ev[q] * inv;

        // stash wh2; then gat[n][c] = sum_j atto[n][j] * Wh2[j][c]
        float* wv = &WH2[w][n * 33 + kq * 8];
        #pragma unroll
        for (int c8 = 0; c8 < 8; ++c8) wv[c8] = wh2[c8];

        float ga[8] = {0.f,0.f,0.f,0.f,0.f,0.f,0.f,0.f};
        #pragma unroll
        for (int jg = 0; jg < 4; ++jg) {
            #pragma unroll
            for (int q = 0; q < 4; ++q) {
                const float aj = __shfl(atto[q], n * 4 + jg);   // att_o[n][4jg+q]
                const float* wr = &WH2[w][(4*jg + q) * 33 + kq * 8];
                #pragma unroll
                for (int c8 = 0; c8 < 8; ++c8) ga[c8] = fmaf(aj, wr[c8], ga[c8]);
            }
        }
        union { unsigned short us[8]; uint4 v; } pk2;
        #pragma unroll
        for (int c8 = 0; c8 < 8; ++c8) pk2.us[c8] = f32_to_bf16_rne(elu1(ga[c8]));
        // rotation swizzle: logical 16B chunk u = n*4+kq -> phys (kq*16 + n + m) & 63
        const int chunk = (kq * 16 + n + m) & 63;
        *(uint4*)((char*)&A[0][0] + m * 1024 + chunk * 16) = pk2.v;
    }

    __syncthreads();

    // ---------------- phase 2: MFMA GEMM, parity-split n-tiles
    const int mi  = w >> 1;             // m-tile
    const int p   = w & 1;              // n-tile parity: tiles 2j+p
    const int col = lane & 15;
    const int g   = lane >> 4;
    const int arow = mi * 16 + col;

    f32x4 acc[11];
    #pragma unroll
    for (int j = 0; j < 11; ++j) acc[j] = (f32x4){0.f, 0.f, 0.f, 0.f};

    const uint4* Bb = (const uint4*)bpack + lane;
    for (int kt = 0; kt < KSTEPS; ++kt) {
        const int chunk = (g * 16 + kt + arow) & 63;
        bf16x8 af = *(const bf16x8*)((const char*)&A[0][0] + arow * 1024 + chunk * 16);
        const uint4* bp = Bb + (kt * NTILE + p) * 64;
        #pragma unroll
        for (int j = 0; j < 11; ++j) {
            uint4 bw = bp[(2 * j) * 64];
            bf16x8 bf;
            memcpy(&bf, &bw, 16);
            acc[j] = __builtin_amdgcn_mfma_f32_16x16x32_bf16(af, bf, acc[j], 0, 0, 0);
        }
    }

    // ---------------- phase 3: epilogue from accumulators
    // lane covers col e = p*16+col of hyp; samples ms = mi*16 + g*4 + r
    const int e = p * 16 + col;
    float yp[4];
    #pragma unroll
    for (int r = 0; r < 4; ++r) {
        const int ms = mi * 16 + g * 4 + r;
        float hs = acc[8][r] + bst[256 + e];
        #pragma unroll
        for (int a = 0; a < 8; ++a)
            hs = fmaf(qs_s[ms * 9 + a], fabsf(acc[a][r] + bst[a * 32 + e]), hs);
        const float hid = elu1(hs);
        yp[r] = hid * fabsf(acc[9][r] + bst[288 + e])
              + fmaxf(acc[10][r] + bst[320 + e], 0.f) * bst[352 + e];
    }
    #pragma unroll
    for (int mask = 1; mask <= 8; mask <<= 1) {
        #pragma unroll
        for (int r = 0; r < 4; ++r) yp[r] += __shfl_xor(yp[r], mask);
    }
    if (col == 0) {
        #pragma unroll
        for (int r = 0; r < 4; ++r) ysum[w][g][r] = yp[r];
    }
    __syncthreads();

    if (t < 32) {
        const int mi2 = t >> 4, g2 = (t >> 2) & 3, r2 = t & 3;
        out[sbase + t] = ysum[mi2 * 2][g2][r2] + ysum[mi2 * 2 + 1][g2][r2] + v2_b[0];
    }
}

// -------------------------------------------------- launch
extern "C" void kernel_launch(void* const* d_in, const int* in_sizes, int n_in,
                              void* d_out, int out_size, void* d_ws, size_t ws_size,
                              hipStream_t stream) {
    const float* agent_qs = (const float*)d_in[0];
    const float* states   = (const float*)d_in[1];
    const float* W_heads  = (const float*)d_in[2];
    const float* a_heads  = (const float*)d_in[3];
    const float* W_out    = (const float*)d_in[4];
    const float* a_out    = (const float*)d_in[5];
    const float* hw1_w    = (const float*)d_in[6];
    const float* hw1_b    = (const float*)d_in[7];
    const float* hb1_w    = (const float*)d_in[8];
    const float* hb1_b    = (const float*)d_in[9];
    const float* hwf_w    = (const float*)d_in[10];
    const float* hwf_b    = (const float*)d_in[11];
    const float* v1_w     = (const float*)d_in[12];
    const float* v1_b     = (const float*)d_in[13];
    const float* v2_w     = (const float*)d_in[14];
    const float* v2_b     = (const float*)d_in[15];

    unsigned short* bpack = (unsigned short*)d_ws;   // 360448 B used

    pack_b<<<(KSTEPS * NTILE * 64 + 255) / 256, 256, 0, stream>>>(hw1_w, hb1_w, hwf_w, v1_w, bpack);
    fused_kernel<<<BT / 32, 256, 0, stream>>>(agent_qs, states,
                                              W_heads, a_heads, W_out, a_out,
                                              bpack,
                                              hw1_b, hb1_b, hwf_b, v1_b, v2_w, v2_b,
                                              (float*)d_out);
}

// Round 6
// 839.862 us; speedup vs baseline: 2.5831x; 2.0015x over previous
//
#include <hip/hip_runtime.h>
#include <hip/hip_bf16.h>
#include <stdint.h>

// QMIX+GAT round 6: lane=(sample,node) GAT -> local softmax, SGPR weights.
// Per block: 32 samples, 4 waves; per wave: 2 quads of 4 samples (16 lanes each).
// Cross-node exchange via small per-wave LDS (in-order DS, no barriers).
// Phase 2/3 (MFMA GEMM s@[hw1|hb1|hwf|v1] + mixing epilogue) identical to R5.

#define N_AGENTS 8
#define BT       (2048 * 128)
#define ALPHA    0.2f
#define NTILE    22            // 352 / 16
#define KSTEPS   16            // 512 / 32

typedef __attribute__((ext_vector_type(8))) short bf16x8;
typedef __attribute__((ext_vector_type(4))) float f32x4;

__device__ __forceinline__ float leaky(float x) { return x >= 0.f ? x : ALPHA * x; }
__device__ __forceinline__ float elu1(float x)  { return x > 0.f ? x : (__expf(x) - 1.f); }

__device__ __forceinline__ unsigned short f32_to_bf16_rne(float x) {
    uint32_t u = __float_as_uint(x);
    u += 0x7fffu + ((u >> 16) & 1u);
    return (unsigned short)(u >> 16);
}
__device__ __forceinline__ uint32_t pack2(float a, float b) {
    return (uint32_t)f32_to_bf16_rne(a) | ((uint32_t)f32_to_bf16_rne(b) << 16);
}
__device__ __forceinline__ float bf_lo(uint32_t u) { return __uint_as_float(u << 16); }
__device__ __forceinline__ float bf_hi(uint32_t u) { return __uint_as_float(u & 0xffff0000u); }

// -------------------------------------------------- kernel P: pack B (bf16 frags)
__global__ __launch_bounds__(256) void pack_b(
    const float* __restrict__ hw1_w, const float* __restrict__ hb1_w,
    const float* __restrict__ hwf_w, const float* __restrict__ v1_w,
    unsigned short* __restrict__ bpack)
{
    const int gi = blockIdx.x * 256 + threadIdx.x;
    if (gi >= KSTEPS * NTILE * 64) return;
    const int l  = gi & 63;
    const int ni = (gi >> 6) % NTILE;
    const int kt = gi / (NTILE * 64);
    const int col = ni * 16 + (l & 15);
    const int k0  = kt * 32 + (l >> 4) * 8;
    const float* src; int stride; int c;
    if (col < 256)      { src = hw1_w; stride = 256; c = col; }
    else if (col < 288) { src = hb1_w; stride = 32;  c = col - 256; }
    else if (col < 320) { src = hwf_w; stride = 32;  c = col - 288; }
    else                { src = v1_w;  stride = 32;  c = col - 320; }
    union { unsigned short u[8]; uint4 v; } pk;
    #pragma unroll
    for (int e = 0; e < 8; ++e) pk.u[e] = f32_to_bf16_rne(src[(long)(k0 + e) * stride + c]);
    ((uint4*)bpack)[gi] = pk.v;
}

// -------------------------------------------------- kernel F
__global__ __launch_bounds__(256) void fused_kernel(
    const float* __restrict__ agent_qs, const float* __restrict__ states,
    const float* __restrict__ W_heads,  const float* __restrict__ a_heads,
    const float* __restrict__ W_out,    const float* __restrict__ a_out,
    const unsigned short* __restrict__ bpack,
    const float* __restrict__ hw1_b, const float* __restrict__ hb1_b,
    const float* __restrict__ hwf_b, const float* __restrict__ v1_b,
    const float* __restrict__ v2_w,  const float* __restrict__ v2_b,
    float* __restrict__ out)
{
    __shared__ unsigned short A[32][512];     // 32 KB, rotation-swizzled 16B chunks
    __shared__ float    whx[4][4][72];        // [wave][g][n*4+k] f32, pad 72
    __shared__ float    es[4][4][20];         // [wave][g][n] exchange, pad 20
    __shared__ uint32_t wh2x[4][4][328];      // [wave][g][n*20 + u] bf16-pairs
    __shared__ float    bst[384];             // hw1_b | hb1_b | hwf_b | v1_b | v2_w
    __shared__ float    qs_s[32 * 9];
    __shared__ float    ysum[4][4][4];

    const int t    = threadIdx.x;
    const int w    = t >> 6;
    const int lane = t & 63;
    const int g    = lane >> 4;      // sample-in-quad / k-group
    const int n    = lane & 15;      // node / col
    const long sbase = (long)blockIdx.x * 32;

    if (t < 256) bst[t] = hw1_b[t];
    if (t < 32) {
        bst[256 + t] = hb1_b[t];
        bst[288 + t] = hwf_b[t];
        bst[320 + t] = v1_b[t];
        bst[352 + t] = v2_w[t];
    }
    qs_s[(t >> 3) * 9 + (t & 7)] = agent_qs[sbase * 8 + t];

    // ---------------- phase 1: GAT, lane = (g=sample, n=node)
    #pragma unroll 1
    for (int q = 0; q < 2; ++q) {
        const int m   = w * 8 + q * 4 + g;
        const long gs = sbase + m;

        float xr[16];
        {
            const float4* xp = (const float4*)(states + gs * 256 + n * 16);
            #pragma unroll
            for (int i = 0; i < 4; ++i) {
                const float4 v = xp[i];
                xr[4*i+0] = v.x; xr[4*i+1] = v.y; xr[4*i+2] = v.z; xr[4*i+3] = v.w;
            }
        }

        float hcat[16];
        #pragma unroll
        for (int h = 0; h < 4; ++h) {
            float wh0 = 0.f, wh1 = 0.f, wh2 = 0.f, wh3 = 0.f;
            #pragma unroll
            for (int f = 0; f < 16; ++f) {
                const float xf = xr[f];
                wh0 = fmaf(xf, W_heads[h*64 + f*4 + 0], wh0);
                wh1 = fmaf(xf, W_heads[h*64 + f*4 + 1], wh1);
                wh2 = fmaf(xf, W_heads[h*64 + f*4 + 2], wh2);
                wh3 = fmaf(xf, W_heads[h*64 + f*4 + 3], wh3);
            }
            const float e1 = wh0*a_heads[h*8+0] + wh1*a_heads[h*8+1]
                           + wh2*a_heads[h*8+2] + wh3*a_heads[h*8+3];
            const float e2 = wh0*a_heads[h*8+4] + wh1*a_heads[h*8+5]
                           + wh2*a_heads[h*8+6] + wh3*a_heads[h*8+7];
            *(float4*)&whx[w][g][n * 4] = make_float4(wh0, wh1, wh2, wh3);
            es[w][g][n] = e2;          // intra-wave: DS in-order, no barrier

            float e2v[16];
            #pragma unroll
            for (int t4 = 0; t4 < 4; ++t4) {
                const float4 v = *(const float4*)&es[w][g][t4 * 4];
                e2v[4*t4+0] = v.x; e2v[4*t4+1] = v.y; e2v[4*t4+2] = v.z; e2v[4*t4+3] = v.w;
            }
            float ee[16]; float mx = -1e30f;
            #pragma unroll
            for (int j = 0; j < 16; ++j) {
                const float tv = leaky(e1 + e2v[j]);
                ee[j] = tv; mx = fmaxf(mx, tv);
            }
            float sum = 0.f;
            #pragma unroll
            for (int j = 0; j < 16; ++j) { ee[j] = __expf(ee[j] - mx); sum += ee[j]; }
            const float inv = 1.f / sum;

            float h0 = 0.f, h1 = 0.f, h2 = 0.f, h3 = 0.f;
            #pragma unroll
            for (int j = 0; j < 16; ++j) {
                const float4 wr = *(const float4*)&whx[w][g][j * 4];
                h0 = fmaf(ee[j], wr.x, h0);
                h1 = fmaf(ee[j], wr.y, h1);
                h2 = fmaf(ee[j], wr.z, h2);
                h3 = fmaf(ee[j], wr.w, h3);
            }
            hcat[h*4+0] = elu1(h0 * inv);
            hcat[h*4+1] = elu1(h1 * inv);
            hcat[h*4+2] = elu1(h2 * inv);
            hcat[h*4+3] = elu1(h3 * inv);
        }

        // ---- layer 2: Wh2 row n (32 cols), e1o/e2o folded
        float e1o = 0.f, e2o = 0.f;
        #pragma unroll 1
        for (int cq = 0; cq < 8; ++cq) {
            float wc[4];
            #pragma unroll
            for (int c4 = 0; c4 < 4; ++c4) {
                const int c = cq * 4 + c4;
                float acc = 0.f;
                #pragma unroll
                for (int f = 0; f < 16; ++f) acc = fmaf(hcat[f], W_out[f*32 + c], acc);
                wc[c4] = acc;
                e1o = fmaf(acc, a_out[c], e1o);
                e2o = fmaf(acc, a_out[32 + c], e2o);
            }
            uint2 pw;
            pw.x = pack2(wc[0], wc[1]);
            pw.y = pack2(wc[2], wc[3]);
            *(uint2*)&wh2x[w][g][n * 20 + cq * 2] = pw;
        }
        es[w][g][n] = e2o;

        float e2v[16];
        #pragma unroll
        for (int t4 = 0; t4 < 4; ++t4) {
            const float4 v = *(const float4*)&es[w][g][t4 * 4];
            e2v[4*t4+0] = v.x; e2v[4*t4+1] = v.y; e2v[4*t4+2] = v.z; e2v[4*t4+3] = v.w;
        }
        float ee[16]; float mx = -1e30f;
        #pragma unroll
        for (int j = 0; j < 16; ++j) {
            const float tv = leaky(e1o + e2v[j]);
            ee[j] = tv; mx = fmaxf(mx, tv);
        }
        float sum = 0.f;
        #pragma unroll
        for (int j = 0; j < 16; ++j) { ee[j] = __expf(ee[j] - mx); sum += ee[j]; }
        const float invo = 1.f / sum;

        float gat[32];
        #pragma unroll
        for (int c = 0; c < 32; ++c) gat[c] = 0.f;
        #pragma unroll
        for (int j = 0; j < 16; ++j) {
            uint32_t ww[16];
            *(uint4*)&ww[0]  = *(const uint4*)&wh2x[w][g][j * 20 + 0];
            *(uint4*)&ww[4]  = *(const uint4*)&wh2x[w][g][j * 20 + 4];
            *(uint4*)&ww[8]  = *(const uint4*)&wh2x[w][g][j * 20 + 8];
            *(uint4*)&ww[12] = *(const uint4*)&wh2x[w][g][j * 20 + 12];
            const float aj = ee[j];
            #pragma unroll
            for (int u = 0; u < 16; ++u) {
                gat[2*u+0] = fmaf(aj, bf_lo(ww[u]), gat[2*u+0]);
                gat[2*u+1] = fmaf(aj, bf_hi(ww[u]), gat[2*u+1]);
            }
        }
        // elu + pack -> A-tile (rotation swizzle, same contract as GEMM read)
        #pragma unroll
        for (int kq = 0; kq < 4; ++kq) {
            union { unsigned short us[8]; uint4 v; } pk;
            #pragma unroll
            for (int i2 = 0; i2 < 8; ++i2)
                pk.us[i2] = f32_to_bf16_rne(elu1(gat[kq*8 + i2] * invo));
            const int chunk = (kq * 16 + n + m) & 63;
            *(uint4*)((char*)&A[0][0] + m * 1024 + chunk * 16) = pk.v;
        }
    }

    __syncthreads();

    // ---------------- phase 2: MFMA GEMM, parity-split n-tiles (validated R5)
    const int mi  = w >> 1;
    const int p   = w & 1;
    const int col = n;
    const int arow = mi * 16 + col;

    f32x4 acc[11];
    #pragma unroll
    for (int j = 0; j < 11; ++j) acc[j] = (f32x4){0.f, 0.f, 0.f, 0.f};

    const uint4* Bb = (const uint4*)bpack + lane;
    for (int kt = 0; kt < KSTEPS; ++kt) {
        const int chunk = (g * 16 + kt + arow) & 63;
        bf16x8 af = *(const bf16x8*)((const char*)&A[0][0] + arow * 1024 + chunk * 16);
        const uint4* bp = Bb + (kt * NTILE + p) * 64;
        #pragma unroll
        for (int j = 0; j < 11; ++j) {
            uint4 bw = bp[(2 * j) * 64];
            bf16x8 bf;
            memcpy(&bf, &bw, 16);
            acc[j] = __builtin_amdgcn_mfma_f32_16x16x32_bf16(af, bf, acc[j], 0, 0, 0);
        }
    }

    // ---------------- phase 3: epilogue from accumulators (validated R5)
    const int e = p * 16 + col;
    float yp[4];
    #pragma unroll
    for (int r = 0; r < 4; ++r) {
        const int ms = mi * 16 + g * 4 + r;
        float hs = acc[8][r] + bst[256 + e];
        #pragma unroll
        for (int a = 0; a < 8; ++a)
            hs = fmaf(qs_s[ms * 9 + a], fabsf(acc[a][r] + bst[a * 32 + e]), hs);
        const float hid = elu1(hs);
        yp[r] = hid * fabsf(acc[9][r] + bst[288 + e])
              + fmaxf(acc[10][r] + bst[320 + e], 0.f) * bst[352 + e];
    }
    #pragma unroll
    for (int mask = 1; mask <= 8; mask <<= 1) {
        #pragma unroll
        for (int r = 0; r < 4; ++r) yp[r] += __shfl_xor(yp[r], mask);
    }
    if (col == 0) {
        #pragma unroll
        for (int r = 0; r < 4; ++r) ysum[w][g][r] = yp[r];
    }
    __syncthreads();

    if (t < 32) {
        const int mi2 = t >> 4, g2 = (t >> 2) & 3, r2 = t & 3;
        out[sbase + t] = ysum[mi2 * 2][g2][r2] + ysum[mi2 * 2 + 1][g2][r2] + v2_b[0];
    }
}

// -------------------------------------------------- launch
extern "C" void kernel_launch(void* const* d_in, const int* in_sizes, int n_in,
                              void* d_out, int out_size, void* d_ws, size_t ws_size,
                              hipStream_t stream) {
    const float* agent_qs = (const float*)d_in[0];
    const float* states   = (const float*)d_in[1];
    const float* W_heads  = (const float*)d_in[2];
    const float* a_heads  = (const float*)d_in[3];
    const float* W_out    = (const float*)d_in[4];
    const float* a_out    = (const float*)d_in[5];
    const float* hw1_w    = (const float*)d_in[6];
    const float* hw1_b    = (const float*)d_in[7];
    const float* hb1_w    = (const float*)d_in[8];
    const float* hb1_b    = (const float*)d_in[9];
    const float* hwf_w    = (const float*)d_in[10];
    const float* hwf_b    = (const float*)d_in[11];
    const float* v1_w     = (const float*)d_in[12];
    const float* v1_b     = (const float*)d_in[13];
    const float* v2_w     = (const float*)d_in[14];
    const float* v2_b     = (const float*)d_in[15];

    unsigned short* bpack = (unsigned short*)d_ws;   // 360448 B used

    pack_b<<<(KSTEPS * NTILE * 64 + 255) / 256, 256, 0, stream>>>(hw1_w, hb1_w, hwf_w, v1_w, bpack);
    fused_kernel<<<BT / 32, 256, 0, stream>>>(agent_qs, states,
                                              W_heads, a_heads, W_out, a_out,
                                              bpack,
                                              hw1_b, hb1_b, hwf_b, v1_b, v2_w, v2_b,
                                              (float*)d_out);
}